// Round 7
// baseline (287.411 us; speedup 1.0000x reference)
//
#include <hip/hip_runtime.h>

#define N_NODES 50000
#define N_EDGES 800000
#define F_IN    128
#define H_DIM   256
#define C_OUT   40
#define MT_TOT  (N_NODES / 16)            // 3125 m-tiles
#define NBIN1   196                       // coarse bins: dst>>8
#define CAP     5120                      // per-bin slab capacity (mean 4082, sigma~64)
#define NCHB    400                       // claim-scatter edge blocks
#define CHSZ    (N_EDGES / NCHB)          // 2000 edges per block
#define CVT_X   (N_NODES * F_IN / 4)      // 1,600,000 float4 groups
#define XVB     ((CVT_X + 255) / 256)     // 6250 xcvt blocks
#define CVT_W1B (H_DIM * F_IN / 4 / 256)  // 32 blocks for W1 cvt

typedef unsigned short u16;
typedef unsigned int   u32;
typedef short bf16x8 __attribute__((ext_vector_type(8)));
typedef float f32x4  __attribute__((ext_vector_type(4)));

__device__ inline float bfbits2f(u16 u) { return __uint_as_float(((u32)u) << 16); }
__device__ inline u16 f2bf(float f) {
    u32 u = __float_as_uint(f);
    u += 0x7fffu + ((u >> 16) & 1u);   // RNE
    return (u16)(u >> 16);
}
__device__ inline u32 pack2(float a, float b) {
    return (u32)f2bf(a) | ((u32)f2bf(b) << 16);
}

// ---- mega: claim-scatter -> (spin) fine pass | x cvt | W1 cvt | Wc = Wo*W2 + bc ----
// Producer blocks [0,NCHB): scatter {src,dst} into bin slabs, then release-signal done.
// Consumer blocks [NCHB, NCHB+NBIN1): acquire-spin until done==NCHB, then fine pass.
// Safe: scatter blocks have lowest IDs (dispatched first); only 196 spinners hold slots;
// xcvt blocks retire and free slots, so producers always make progress.
__global__ __launch_bounds__(256) void mega_k(const int* __restrict__ src, const int* __restrict__ dst,
                                              int* __restrict__ bincnt, int* __restrict__ done,
                                              uint2* __restrict__ T,
                                              u32* __restrict__ rowinfo, float* __restrict__ dinv,
                                              u32* __restrict__ edata,
                                              const float4* __restrict__ x, uint2* __restrict__ xb,
                                              const float4* __restrict__ W1, uint2* __restrict__ W1b,
                                              const float* __restrict__ W2, const float* __restrict__ Wo,
                                              const float* __restrict__ b2, const float* __restrict__ bo,
                                              u16* __restrict__ Wcb, float* __restrict__ bc) {
    __shared__ int hist[NBIN1];
    __shared__ int curp[NBIN1];
    __shared__ int hcnt[256];
    __shared__ int sc[256];
    __shared__ int cur[256];
    __shared__ float red[256];
    const int t = threadIdx.x;
    if (blockIdx.x < NCHB) {               // ---- claim-scatter chunk (2000 edges) ----
        const int b = blockIdx.x;
        if (t < NBIN1) hist[t] = 0;
        __syncthreads();
        for (int i = b * CHSZ + t; i < (b + 1) * CHSZ; i += 256)
            atomicAdd(&hist[dst[i] >> 8], 1);
        __syncthreads();
        if (t < NBIN1) curp[t] = atomicAdd(&bincnt[t], hist[t]);   // claim within-bin range
        __syncthreads();
        for (int i = b * CHSZ + t; i < (b + 1) * CHSZ; i += 256) {
            const int s = src[i], d = dst[i];
            const int bin = d >> 8;
            const int idx = atomicAdd(&curp[bin], 1);
            uint2 ed; ed.x = (u32)s; ed.y = (u32)d;
            T[(size_t)bin * CAP + idx] = ed;
        }
        __syncthreads();
        if (t == 0) {
            __threadfence();               // publish T/bincnt before signaling
            __hip_atomic_fetch_add(done, 1, __ATOMIC_RELEASE, __HIP_MEMORY_SCOPE_AGENT);
        }
        return;
    }
    if (blockIdx.x < NCHB + NBIN1) {       // ---- fine pass (waits for all scatter blocks) ----
        if (t == 0) {
            while (__hip_atomic_load(done, __ATOMIC_ACQUIRE, __HIP_MEMORY_SCOPE_AGENT) != NCHB)
                __builtin_amdgcn_s_sleep(8);
        }
        __syncthreads();
        const int g = blockIdx.x - NCHB;
        const int nbeg = g * CAP;
        const int nend = nbeg + bincnt[g];
        hcnt[t] = 0;
        __syncthreads();
        for (int i = nbeg + t; i < nend; i += 256)
            atomicAdd(&hcnt[T[i].y & 255], 1);
        __syncthreads();
        const int my = hcnt[t];
        sc[t] = my;
        __syncthreads();
        for (int off = 1; off < 256; off <<= 1) {
            int u = (t >= off) ? sc[t - off] : 0;
            __syncthreads();
            sc[t] += u;
            __syncthreads();
        }
        const int rbeg = nbeg + sc[t] - my; // slab global position (< 196*5120 < 2^20)
        const int node = g * 256 + t;
        if (node < N_NODES) {
            rowinfo[node] = ((u32)my << 20) | (u32)rbeg;
            dinv[node] = rsqrtf((float)my + 1.0f);
        }
        cur[t] = rbeg;
        __syncthreads();
        for (int i = nbeg + t; i < nend; i += 256) {   // T re-read: L2-resident per bin
            const uint2 e = T[i];
            const int pos = atomicAdd(&cur[e.y & 255], 1);
            edata[pos] = e.x;
        }
        return;
    }
    if (blockIdx.x < NCHB + NBIN1 + XVB) { // ---- x fp32 -> bf16 (no scale) ----
        const int i = (blockIdx.x - NCHB - NBIN1) * 256 + t;
        if (i >= CVT_X) return;
        float4 v = x[i];
        uint2 o; o.x = pack2(v.x, v.y); o.y = pack2(v.z, v.w);
        xb[i] = o;
        return;
    }
    if (blockIdx.x < NCHB + NBIN1 + XVB + CVT_W1B) {   // ---- W1 fp32 -> bf16 ----
        int i = (blockIdx.x - NCHB - NBIN1 - XVB) * 256 + t;
        float4 v = W1[i];
        uint2 o; o.x = pack2(v.x, v.y); o.y = pack2(v.z, v.w);
        W1b[i] = o;
        return;
    }
    const int c = blockIdx.x - NCHB - NBIN1 - XVB - CVT_W1B;   // 0..39: Wc row
    float acc = 0.f;
    for (int o = 0; o < H_DIM; o += 8) {
        float w2v[8];
#pragma unroll
        for (int j = 0; j < 8; j++) w2v[j] = W2[(size_t)(o + j) * H_DIM + t];
#pragma unroll
        for (int j = 0; j < 8; j++) acc += Wo[(size_t)c * H_DIM + o + j] * w2v[j];
    }
    Wcb[(size_t)c * H_DIM + t] = f2bf(acc);
    red[t] = b2[t] * Wo[(size_t)c * H_DIM + t];
    __syncthreads();
    for (int off = 128; off > 0; off >>= 1) {
        if (t < off) red[t] += red[t + off];
        __syncthreads();
    }
    if (t == 0) bc[c] = red[0] + bo[c];
}

// ---- gather width-128: aggx[d] = dd * (sum_s dinv[s]*x[s] + dd*x[d]) ----
__global__ __launch_bounds__(256) void gather1_k(const u32* __restrict__ xb,
                                                 const u32* __restrict__ rowinfo,
                                                 const u32* __restrict__ edata,
                                                 const float* __restrict__ dinv,
                                                 u32* __restrict__ aggx) {
    const int node = __builtin_amdgcn_readfirstlane(blockIdx.x * 4 + (threadIdx.x >> 6));
    const int lane = threadIdx.x & 63;
    if (node >= N_NODES) return;
    const u32 info = __builtin_amdgcn_readfirstlane(rowinfo[node]);
    const int beg = (int)(info & 0xFFFFFu);
    const int end = beg + (int)(info >> 20);
    const float dd = dinv[node];
    const u32 vs = xb[(size_t)node * 64 + lane];
    float a0 = dd * bfbits2f((u16)vs);
    float a1 = dd * bfbits2f((u16)(vs >> 16));
    int e = beg;
    for (; e + 7 < end; e += 8) {
        u32 s8[8];
#pragma unroll
        for (int j = 0; j < 8; j++) s8[j] = edata[e + j];
        float dv8[8];
#pragma unroll
        for (int j = 0; j < 8; j++) dv8[j] = dinv[s8[j]];
        u32 v[8];
#pragma unroll
        for (int j = 0; j < 8; j++) v[j] = xb[(size_t)s8[j] * 64 + lane];
#pragma unroll
        for (int j = 0; j < 8; j++) {
            a0 += dv8[j] * bfbits2f((u16)v[j]);
            a1 += dv8[j] * bfbits2f((u16)(v[j] >> 16));
        }
    }
    for (; e < end; e++) {
        const u32 s = edata[e];
        const float dv = dinv[s];
        const u32 v0 = xb[(size_t)s * 64 + lane];
        a0 += dv * bfbits2f((u16)v0);
        a1 += dv * bfbits2f((u16)(v0 >> 16));
    }
    aggx[(size_t)node * 64 + lane] = pack2(dd * a0, dd * a1);
}

// ---- fused layer-1 GEMM + t-GEMM; epilogue pre-scales t by dinv[row]; tb packed [N][40] ----
__global__ __launch_bounds__(256) void bgemm1f_k(const u16* __restrict__ X,      // aggxb [N][128]
                                                 const u16* __restrict__ W1b,
                                                 const float* __restrict__ b1,
                                                 const u16* __restrict__ Wcb,    // [40][256] bf16
                                                 const float* __restrict__ dinv,
                                                 u16* __restrict__ tb) {         // [N][40] = dinv*t
    constexpr int KF1 = F_IN / 32;   // 4
    constexpr int KF2 = H_DIM / 32;  // 8
    __shared__ __align__(16) u16 hs[2][16][H_DIM + 8];
    const int wave = threadIdx.x >> 6;
    const int lane = threadIdx.x & 63;
    const int quad = lane >> 4;
    const int nn = lane & 15;
    const int ngbase = wave * 64;

    bf16x8 Bf[4][KF1];
    float bb[4];
#pragma unroll
    for (int j = 0; j < 4; j++) {
        const int wr = ngbase + j * 16 + nn;
#pragma unroll
        for (int kf = 0; kf < KF1; kf++)
            Bf[j][kf] = *(const bf16x8*)(W1b + (size_t)wr * F_IN + kf * 32 + quad * 8);
        bb[j] = b1[wr];
    }
    bf16x8 Bh[KF2];
    {
        int hr = wave * 16 + nn;
        if (hr > C_OUT - 1) hr = C_OUT - 1;
#pragma unroll
        for (int kf = 0; kf < KF2; kf++)
            Bh[kf] = *(const bf16x8*)(Wcb + (size_t)hr * H_DIM + kf * 32 + quad * 8);
    }

    int mt = blockIdx.x;
    if (mt >= MT_TOT) return;
    const int stride = gridDim.x;
    int buf = 0;

    bf16x8 Acur[KF1], Anext[KF1];
    {
        const u16* ap = X + (size_t)(mt * 16 + nn) * F_IN + quad * 8;
#pragma unroll
        for (int kf = 0; kf < KF1; kf++) Acur[kf] = *(const bf16x8*)(ap + kf * 32);
    }

    while (true) {
        const int mtn = mt + stride;
        if (mtn < MT_TOT) {
            const u16* ap = X + (size_t)(mtn * 16 + nn) * F_IN + quad * 8;
#pragma unroll
            for (int kf = 0; kf < KF1; kf++) Anext[kf] = *(const bf16x8*)(ap + kf * 32);
        }

        f32x4 acc[4];
#pragma unroll
        for (int j = 0; j < 4; j++) acc[j] = (f32x4){0.f, 0.f, 0.f, 0.f};
#pragma unroll
        for (int kf = 0; kf < KF1; kf++)
#pragma unroll
            for (int j = 0; j < 4; j++)
                acc[j] = __builtin_amdgcn_mfma_f32_16x16x32_bf16(Acur[kf], Bf[j][kf], acc[j], 0, 0, 0);

#pragma unroll
        for (int j = 0; j < 4; j++)
#pragma unroll
            for (int r = 0; r < 4; r++)
                hs[buf][quad * 4 + r][ngbase + j * 16 + nn] = f2bf(fmaxf(acc[j][r] + bb[j], 0.f));
        __syncthreads();

        if (wave < 3) {
            f32x4 ah = (f32x4){0.f, 0.f, 0.f, 0.f};
#pragma unroll
            for (int kf = 0; kf < KF2; kf++) {
                bf16x8 af = *(const bf16x8*)(&hs[buf][nn][kf * 32 + quad * 8]);
                ah = __builtin_amdgcn_mfma_f32_16x16x32_bf16(af, Bh[kf], ah, 0, 0, 0);
            }
            const int col = wave * 16 + nn;   // 0..47; only <40 stored
            if (col < C_OUT) {
#pragma unroll
                for (int r = 0; r < 4; r++) {
                    const int row = mt * 16 + quad * 4 + r;
                    tb[(size_t)row * C_OUT + col] = f2bf(dinv[row] * ah[r]);
                }
            }
        }

        if (mtn >= MT_TOT) break;
#pragma unroll
        for (int kf = 0; kf < KF1; kf++) Acur[kf] = Anext[kf];
        mt = mtn;
        buf ^= 1;
    }
}

// ---- final gather width 40 (packed 80B rows): out[d] = dd * (sum ts[s] + ts[d]) + bc ----
__global__ __launch_bounds__(256) void gatherO_k(const u32* __restrict__ tb,     // [N][C_OUT/2]
                                                 const u32* __restrict__ rowinfo,
                                                 const u32* __restrict__ edata,
                                                 const float* __restrict__ dinv,
                                                 const float* __restrict__ bc,
                                                 float* __restrict__ out) {
    const int node = __builtin_amdgcn_readfirstlane(blockIdx.x * 4 + (threadIdx.x >> 6));
    const int lane = threadIdx.x & 63;
    if (node >= N_NODES) return;
    const int lc = lane & 31;
    const bool act = (lc < C_OUT / 2);
    const u32 info = __builtin_amdgcn_readfirstlane(rowinfo[node]);
    const int beg = (int)(info & 0xFFFFFu);
    const int end = beg + (int)(info >> 20);
    const float dd = dinv[node];
    const u32 vs = act ? tb[(size_t)node * (C_OUT / 2) + lc] : 0u;
    float a0 = bfbits2f((u16)vs);
    float a1 = bfbits2f((u16)(vs >> 16));
    int e = beg;
    for (; e + 7 < end; e += 8) {
        u32 s8[8];
#pragma unroll
        for (int j = 0; j < 8; j++) s8[j] = edata[e + j];
        u32 v[8];
#pragma unroll
        for (int j = 0; j < 8; j++) v[j] = act ? tb[(size_t)s8[j] * (C_OUT / 2) + lc] : 0u;
#pragma unroll
        for (int j = 0; j < 8; j++) {
            a0 += bfbits2f((u16)v[j]);
            a1 += bfbits2f((u16)(v[j] >> 16));
        }
    }
    for (; e < end; e++) {
        const u32 v0 = act ? tb[(size_t)edata[e] * (C_OUT / 2) + lc] : 0u;
        a0 += bfbits2f((u16)v0);
        a1 += bfbits2f((u16)(v0 >> 16));
    }
    if (act) {
        float2 o;
        o.x = dd * a0 + bc[2 * lc];
        o.y = dd * a1 + bc[2 * lc + 1];
        *(float2*)(out + (size_t)node * C_OUT + 2 * lc) = o;
    }
}

extern "C" void kernel_launch(void* const* d_in, const int* in_sizes, int n_in,
                              void* d_out, int out_size, void* d_ws, size_t ws_size,
                              hipStream_t stream) {
    const float* x    = (const float*)d_in[0];
    const int*   ei   = (const int*)d_in[1];
    const float* W1   = (const float*)d_in[2];
    const float* b1   = (const float*)d_in[3];
    const float* W2   = (const float*)d_in[4];
    const float* b2   = (const float*)d_in[5];
    const float* Wout = (const float*)d_in[6];
    const float* bout = (const float*)d_in[7];
    float* out = (float*)d_out;

    const int* src = ei;            // edge_index[0]
    const int* dst = ei + N_EDGES;  // edge_index[1]

    // workspace (~43 MB)
    char* ws = (char*)d_ws;
    size_t o = 0;
    auto alloc = [&](size_t bytes) { size_t p = o; o = (o + bytes + 255) & ~(size_t)255; return p; };
    int*   bincnt = (int*)(ws + alloc((size_t)(NBIN1 + 1) * 4));        // +1: done counter
    int*   done   = bincnt + NBIN1;
    float* dinv   = (float*)(ws + alloc((size_t)N_NODES * 4));
    u32*   rowinfo= (u32*)(ws + alloc((size_t)N_NODES * 4));
    uint2* T      = (uint2*)(ws + alloc((size_t)NBIN1 * CAP * 8));      // 8.0 MB slabs
    u32*   edata  = (u32*)(ws + alloc((size_t)NBIN1 * CAP * 4));        // 4.0 MB slabs
    u16*   xb     = (u16*)(ws + alloc((size_t)N_NODES * F_IN * 2));     // 12.8 MB
    u16*   aggxb  = (u16*)(ws + alloc((size_t)N_NODES * F_IN * 2));     // 12.8 MB
    u16*   tb     = (u16*)(ws + alloc((size_t)N_NODES * C_OUT * 2 + 256)); // 4 MB packed
    u16*   W1b    = (u16*)(ws + alloc((size_t)H_DIM * F_IN * 2));
    u16*   Wcb    = (u16*)(ws + alloc((size_t)C_OUT * H_DIM * 2));
    float* bc     = (float*)(ws + alloc((size_t)C_OUT * 4));

    // zero bin counters + done (ws is poisoned every iteration)
    hipMemsetAsync(bincnt, 0, (size_t)(NBIN1 + 1) * 4, stream);
    // mega: scatter -> (spin) fine pass | x cvt | W1 cvt | Wc/bc, single launch
    mega_k<<<NCHB + NBIN1 + XVB + CVT_W1B + C_OUT, 256, 0, stream>>>(
        src, dst, bincnt, done, T, rowinfo, dinv, edata,
        (const float4*)x, (uint2*)xb,
        (const float4*)W1, (uint2*)W1b, W2, Wout, b2, bout, Wcb, bc);

    // layer 1 aggregate-first: aggx = dd*(sum dinv[s]*xs + dd*x_self)
    gather1_k<<<(N_NODES + 3) / 4, 256, 0, stream>>>((const u32*)xb, rowinfo, edata, dinv, (u32*)aggxb);
    // fused: h1 = relu(aggx@W1^T+b1) [LDS only] ; tb = dinv*(h1@Wc^T) packed [N][40]
    bgemm1f_k<<<768, 256, 0, stream>>>(aggxb, W1b, b1, Wcb, dinv, tb);
    // final: out = dd*(sum ts + ts_self) + bc
    gatherO_k<<<(N_NODES + 3) / 4, 256, 0, stream>>>((const u32*)tb, rowinfo, edata, dinv, bc, out);
}

// Round 8
// 187.467 us; speedup vs baseline: 1.5331x; 1.5331x over previous
//
#include <hip/hip_runtime.h>

#define N_NODES 50000
#define N_EDGES 800000
#define F_IN    128
#define H_DIM   256
#define C_OUT   40
#define MT_TOT  (N_NODES / 16)            // 3125 m-tiles
#define NBIN1   196                       // coarse bins: dst>>8
#define CAP     5120                      // per-bin slab capacity (mean 4082, sigma~64)
#define NCHB    200                       // claim-scatter edge blocks
#define CHSZ    (N_EDGES / NCHB)          // 4000 edges per block
#define CVT_X   (N_NODES * F_IN / 4)      // 1,600,000 float4 groups
#define XVB     ((CVT_X + 255) / 256)     // 6250 xcvt blocks
#define CVT_W1B (H_DIM * F_IN / 4 / 256)  // 32 blocks for W1 cvt

typedef unsigned short u16;
typedef unsigned int   u32;
typedef short bf16x8 __attribute__((ext_vector_type(8)));
typedef float f32x4  __attribute__((ext_vector_type(4)));

__device__ inline float bfbits2f(u16 u) { return __uint_as_float(((u32)u) << 16); }
__device__ inline u16 f2bf(float f) {
    u32 u = __float_as_uint(f);
    u += 0x7fffu + ((u >> 16) & 1u);   // RNE
    return (u16)(u >> 16);
}
__device__ inline u32 pack2(float a, float b) {
    return (u32)f2bf(a) | ((u32)f2bf(b) << 16);
}

// ---- mega1: claim-scatter into bin slabs | x cvt (unscaled) | W1 cvt | Wc = Wo*W2 + bc ----
__global__ __launch_bounds__(256) void mega1_k(const int* __restrict__ src, const int* __restrict__ dst,
                                               int* __restrict__ bincnt, uint2* __restrict__ T,
                                               const float4* __restrict__ x, uint2* __restrict__ xb,
                                               const float4* __restrict__ W1, uint2* __restrict__ W1b,
                                               const float* __restrict__ W2, const float* __restrict__ Wo,
                                               const float* __restrict__ b2, const float* __restrict__ bo,
                                               u16* __restrict__ Wcb, float* __restrict__ bc) {
    __shared__ int hist[NBIN1];
    __shared__ int curp[NBIN1];
    __shared__ float red[256];
    const int t = threadIdx.x;
    if (blockIdx.x < NCHB) {               // claim-scatter chunk (2000*2 edges)
        const int b = blockIdx.x;
        if (t < NBIN1) hist[t] = 0;
        __syncthreads();
        for (int i = b * CHSZ + t; i < (b + 1) * CHSZ; i += 256)
            atomicAdd(&hist[dst[i] >> 8], 1);
        __syncthreads();
        if (t < NBIN1) curp[t] = atomicAdd(&bincnt[t], hist[t]);   // claim within-bin range
        __syncthreads();
        for (int i = b * CHSZ + t; i < (b + 1) * CHSZ; i += 256) {
            const int s = src[i], d = dst[i];
            const int bin = d >> 8;
            const int idx = atomicAdd(&curp[bin], 1);
            uint2 ed; ed.x = (u32)s; ed.y = (u32)d;
            T[(size_t)bin * CAP + idx] = ed;
        }
        return;
    }
    if (blockIdx.x < NCHB + XVB) {         // x fp32 -> bf16 (no scale)
        const int i = (blockIdx.x - NCHB) * 256 + t;
        if (i >= CVT_X) return;
        float4 v = x[i];
        uint2 o; o.x = pack2(v.x, v.y); o.y = pack2(v.z, v.w);
        xb[i] = o;
        return;
    }
    if (blockIdx.x < NCHB + XVB + CVT_W1B) {   // W1 fp32 -> bf16
        int i = (blockIdx.x - NCHB - XVB) * 256 + t;
        float4 v = W1[i];
        uint2 o; o.x = pack2(v.x, v.y); o.y = pack2(v.z, v.w);
        W1b[i] = o;
        return;
    }
    const int c = blockIdx.x - NCHB - XVB - CVT_W1B;   // 0..39: Wc row
    float acc = 0.f;
    for (int o = 0; o < H_DIM; o += 8) {
        float w2v[8];
#pragma unroll
        for (int j = 0; j < 8; j++) w2v[j] = W2[(size_t)(o + j) * H_DIM + t];
#pragma unroll
        for (int j = 0; j < 8; j++) acc += Wo[(size_t)c * H_DIM + o + j] * w2v[j];
    }
    Wcb[(size_t)c * H_DIM + t] = f2bf(acc);
    red[t] = b2[t] * Wo[(size_t)c * H_DIM + t];
    __syncthreads();
    for (int off = 128; off > 0; off >>= 1) {
        if (t < off) red[t] += red[t + off];
        __syncthreads();
    }
    if (t == 0) bc[c] = red[0] + bo[c];
}

// ---- p3: fine hist -> rowinfo(beg|cnt) + dinv + scatter src-only edata (slab layout) ----
__global__ __launch_bounds__(256) void p3_k(const uint2* __restrict__ T, const int* __restrict__ bincnt,
                                            u32* __restrict__ rowinfo, float* __restrict__ dinv,
                                            u32* __restrict__ edata) {
    __shared__ int hcnt[256];
    __shared__ int sc[256];
    __shared__ int cur[256];
    const int t = threadIdx.x;
    const int g = blockIdx.x;
    const int nbeg = g * CAP;
    const int nend = nbeg + bincnt[g];
    hcnt[t] = 0;
    __syncthreads();
    for (int i = nbeg + t; i < nend; i += 256)
        atomicAdd(&hcnt[T[i].y & 255], 1);
    __syncthreads();
    const int my = hcnt[t];
    sc[t] = my;
    __syncthreads();
    for (int off = 1; off < 256; off <<= 1) {
        int u = (t >= off) ? sc[t - off] : 0;
        __syncthreads();
        sc[t] += u;
        __syncthreads();
    }
    const int rbeg = nbeg + sc[t] - my;     // slab-relative global position (< 196*5120 < 2^20)
    const int node = g * 256 + t;
    if (node < N_NODES) {
        rowinfo[node] = ((u32)my << 20) | (u32)rbeg;
        dinv[node] = rsqrtf((float)my + 1.0f);
    }
    cur[t] = rbeg;
    __syncthreads();
    for (int i = nbeg + t; i < nend; i += 256) {    // T re-read: L2-resident per bin
        const uint2 e = T[i];
        const int pos = atomicAdd(&cur[e.y & 255], 1);
        edata[pos] = e.x;
    }
}

// ---- gather width-128: aggx[d] = dd * (sum_s dinv[s]*x[s] + dd*x[d]) ----
__global__ __launch_bounds__(256) void gather1_k(const u32* __restrict__ xb,
                                                 const u32* __restrict__ rowinfo,
                                                 const u32* __restrict__ edata,
                                                 const float* __restrict__ dinv,
                                                 u32* __restrict__ aggx) {
    const int node = __builtin_amdgcn_readfirstlane(blockIdx.x * 4 + (threadIdx.x >> 6));
    const int lane = threadIdx.x & 63;
    if (node >= N_NODES) return;
    const u32 info = __builtin_amdgcn_readfirstlane(rowinfo[node]);
    const int beg = (int)(info & 0xFFFFFu);
    const int end = beg + (int)(info >> 20);
    const float dd = dinv[node];
    const u32 vs = xb[(size_t)node * 64 + lane];
    float a0 = dd * bfbits2f((u16)vs);
    float a1 = dd * bfbits2f((u16)(vs >> 16));
    int e = beg;
    for (; e + 7 < end; e += 8) {
        u32 s8[8];
#pragma unroll
        for (int j = 0; j < 8; j++) s8[j] = edata[e + j];
        float dv8[8];
#pragma unroll
        for (int j = 0; j < 8; j++) dv8[j] = dinv[s8[j]];
        u32 v[8];
#pragma unroll
        for (int j = 0; j < 8; j++) v[j] = xb[(size_t)s8[j] * 64 + lane];
#pragma unroll
        for (int j = 0; j < 8; j++) {
            a0 += dv8[j] * bfbits2f((u16)v[j]);
            a1 += dv8[j] * bfbits2f((u16)(v[j] >> 16));
        }
    }
    for (; e < end; e++) {
        const u32 s = edata[e];
        const float dv = dinv[s];
        const u32 v0 = xb[(size_t)s * 64 + lane];
        a0 += dv * bfbits2f((u16)v0);
        a1 += dv * bfbits2f((u16)(v0 >> 16));
    }
    aggx[(size_t)node * 64 + lane] = pack2(dd * a0, dd * a1);
}

// ---- fused layer-1 GEMM + t-GEMM; epilogue pre-scales t by dinv[row]; tb packed [N][40] ----
__global__ __launch_bounds__(256) void bgemm1f_k(const u16* __restrict__ X,      // aggxb [N][128]
                                                 const u16* __restrict__ W1b,
                                                 const float* __restrict__ b1,
                                                 const u16* __restrict__ Wcb,    // [40][256] bf16
                                                 const float* __restrict__ dinv,
                                                 u16* __restrict__ tb) {         // [N][40] = dinv*t
    constexpr int KF1 = F_IN / 32;   // 4
    constexpr int KF2 = H_DIM / 32;  // 8
    __shared__ __align__(16) u16 hs[2][16][H_DIM + 8];
    const int wave = threadIdx.x >> 6;
    const int lane = threadIdx.x & 63;
    const int quad = lane >> 4;
    const int nn = lane & 15;
    const int ngbase = wave * 64;

    bf16x8 Bf[4][KF1];
    float bb[4];
#pragma unroll
    for (int j = 0; j < 4; j++) {
        const int wr = ngbase + j * 16 + nn;
#pragma unroll
        for (int kf = 0; kf < KF1; kf++)
            Bf[j][kf] = *(const bf16x8*)(W1b + (size_t)wr * F_IN + kf * 32 + quad * 8);
        bb[j] = b1[wr];
    }
    bf16x8 Bh[KF2];
    {
        int hr = wave * 16 + nn;
        if (hr > C_OUT - 1) hr = C_OUT - 1;
#pragma unroll
        for (int kf = 0; kf < KF2; kf++)
            Bh[kf] = *(const bf16x8*)(Wcb + (size_t)hr * H_DIM + kf * 32 + quad * 8);
    }

    int mt = blockIdx.x;
    if (mt >= MT_TOT) return;
    const int stride = gridDim.x;
    int buf = 0;

    bf16x8 Acur[KF1], Anext[KF1];
    {
        const u16* ap = X + (size_t)(mt * 16 + nn) * F_IN + quad * 8;
#pragma unroll
        for (int kf = 0; kf < KF1; kf++) Acur[kf] = *(const bf16x8*)(ap + kf * 32);
    }

    while (true) {
        const int mtn = mt + stride;
        if (mtn < MT_TOT) {
            const u16* ap = X + (size_t)(mtn * 16 + nn) * F_IN + quad * 8;
#pragma unroll
            for (int kf = 0; kf < KF1; kf++) Anext[kf] = *(const bf16x8*)(ap + kf * 32);
        }

        f32x4 acc[4];
#pragma unroll
        for (int j = 0; j < 4; j++) acc[j] = (f32x4){0.f, 0.f, 0.f, 0.f};
#pragma unroll
        for (int kf = 0; kf < KF1; kf++)
#pragma unroll
            for (int j = 0; j < 4; j++)
                acc[j] = __builtin_amdgcn_mfma_f32_16x16x32_bf16(Acur[kf], Bf[j][kf], acc[j], 0, 0, 0);

#pragma unroll
        for (int j = 0; j < 4; j++)
#pragma unroll
            for (int r = 0; r < 4; r++)
                hs[buf][quad * 4 + r][ngbase + j * 16 + nn] = f2bf(fmaxf(acc[j][r] + bb[j], 0.f));
        __syncthreads();

        if (wave < 3) {
            f32x4 ah = (f32x4){0.f, 0.f, 0.f, 0.f};
#pragma unroll
            for (int kf = 0; kf < KF2; kf++) {
                bf16x8 af = *(const bf16x8*)(&hs[buf][nn][kf * 32 + quad * 8]);
                ah = __builtin_amdgcn_mfma_f32_16x16x32_bf16(af, Bh[kf], ah, 0, 0, 0);
            }
            const int col = wave * 16 + nn;   // 0..47; only <40 stored
            if (col < C_OUT) {
#pragma unroll
                for (int r = 0; r < 4; r++) {
                    const int row = mt * 16 + quad * 4 + r;
                    tb[(size_t)row * C_OUT + col] = f2bf(dinv[row] * ah[r]);
                }
            }
        }

        if (mtn >= MT_TOT) break;
#pragma unroll
        for (int kf = 0; kf < KF1; kf++) Acur[kf] = Anext[kf];
        mt = mtn;
        buf ^= 1;
    }
}

// ---- final gather width 40, 2 nodes/wave (32-lane halves, 20 active each) ----
// out[d] = dd * (sum ts[s] + ts[d]) + bc
__global__ __launch_bounds__(256) void gatherO_k(const u32* __restrict__ tb,     // [N][C_OUT/2]
                                                 const u32* __restrict__ rowinfo,
                                                 const u32* __restrict__ edata,
                                                 const float* __restrict__ dinv,
                                                 const float* __restrict__ bc,
                                                 float* __restrict__ out) {
    const int lane = threadIdx.x & 63;
    const int half = lane >> 5;
    const int lc   = lane & 31;
    const bool act = (lc < C_OUT / 2);
    const int node = blockIdx.x * 8 + (threadIdx.x >> 6) * 2 + half;
    if (node >= N_NODES) return;
    const u32 info = rowinfo[node];         // uniform within half-wave -> HW broadcast
    const int beg = (int)(info & 0xFFFFFu);
    const int end = beg + (int)(info >> 20);
    const float dd = dinv[node];
    const u32 vs = act ? tb[(size_t)node * (C_OUT / 2) + lc] : 0u;
    float a0 = bfbits2f((u16)vs);
    float a1 = bfbits2f((u16)(vs >> 16));
    int e = beg;
    for (; e + 7 < end; e += 8) {
        u32 s8[8];
#pragma unroll
        for (int j = 0; j < 8; j++) s8[j] = edata[e + j];
        u32 v[8];
#pragma unroll
        for (int j = 0; j < 8; j++) v[j] = act ? tb[(size_t)s8[j] * (C_OUT / 2) + lc] : 0u;
#pragma unroll
        for (int j = 0; j < 8; j++) {
            a0 += bfbits2f((u16)v[j]);
            a1 += bfbits2f((u16)(v[j] >> 16));
        }
    }
    for (; e < end; e++) {
        const u32 v0 = act ? tb[(size_t)edata[e] * (C_OUT / 2) + lc] : 0u;
        a0 += bfbits2f((u16)v0);
        a1 += bfbits2f((u16)(v0 >> 16));
    }
    if (act) {
        float2 o;
        o.x = dd * a0 + bc[2 * lc];
        o.y = dd * a1 + bc[2 * lc + 1];
        *(float2*)(out + (size_t)node * C_OUT + 2 * lc) = o;
    }
}

extern "C" void kernel_launch(void* const* d_in, const int* in_sizes, int n_in,
                              void* d_out, int out_size, void* d_ws, size_t ws_size,
                              hipStream_t stream) {
    const float* x    = (const float*)d_in[0];
    const int*   ei   = (const int*)d_in[1];
    const float* W1   = (const float*)d_in[2];
    const float* b1   = (const float*)d_in[3];
    const float* W2   = (const float*)d_in[4];
    const float* b2   = (const float*)d_in[5];
    const float* Wout = (const float*)d_in[6];
    const float* bout = (const float*)d_in[7];
    float* out = (float*)d_out;

    const int* src = ei;            // edge_index[0]
    const int* dst = ei + N_EDGES;  // edge_index[1]

    // workspace (~43 MB)
    char* ws = (char*)d_ws;
    size_t o = 0;
    auto alloc = [&](size_t bytes) { size_t p = o; o = (o + bytes + 255) & ~(size_t)255; return p; };
    int*   bincnt = (int*)(ws + alloc((size_t)NBIN1 * 4));
    float* dinv   = (float*)(ws + alloc((size_t)N_NODES * 4));
    u32*   rowinfo= (u32*)(ws + alloc((size_t)N_NODES * 4));
    uint2* T      = (uint2*)(ws + alloc((size_t)NBIN1 * CAP * 8));      // 8.0 MB slabs
    u32*   edata  = (u32*)(ws + alloc((size_t)NBIN1 * CAP * 4));        // 4.0 MB slabs
    u16*   xb     = (u16*)(ws + alloc((size_t)N_NODES * F_IN * 2));     // 12.8 MB
    u16*   aggxb  = (u16*)(ws + alloc((size_t)N_NODES * F_IN * 2));     // 12.8 MB
    u16*   tb     = (u16*)(ws + alloc((size_t)N_NODES * C_OUT * 2 + 256)); // 4 MB packed
    u16*   W1b    = (u16*)(ws + alloc((size_t)H_DIM * F_IN * 2));
    u16*   Wcb    = (u16*)(ws + alloc((size_t)C_OUT * H_DIM * 2));
    float* bc     = (float*)(ws + alloc((size_t)C_OUT * 4));

    // zero bin counters (ws is poisoned every iteration)
    hipMemsetAsync(bincnt, 0, (size_t)NBIN1 * 4, stream);
    // mega1: claim-scatter into slabs | x cvt | W1 cvt | Wc/bc  (all sections independent)
    mega1_k<<<NCHB + XVB + CVT_W1B + C_OUT, 256, 0, stream>>>(
        src, dst, bincnt, T, (const float4*)x, (uint2*)xb,
        (const float4*)W1, (uint2*)W1b, W2, Wout, b2, bout, Wcb, bc);
    // fine pass: rowinfo + dinv + edata scatter (slab layout)
    p3_k<<<NBIN1, 256, 0, stream>>>(T, bincnt, rowinfo, dinv, edata);

    // layer 1 aggregate-first: aggx = dd*(sum dinv[s]*xs + dd*x_self)
    gather1_k<<<(N_NODES + 3) / 4, 256, 0, stream>>>((const u32*)xb, rowinfo, edata, dinv, (u32*)aggxb);
    // fused: h1 = relu(aggx@W1^T+b1) [LDS only] ; tb = dinv*(h1@Wc^T) packed [N][40]
    bgemm1f_k<<<768, 256, 0, stream>>>(aggxb, W1b, b1, Wcb, dinv, tb);
    // final: out = dd*(sum ts + ts_self) + bc, 2 nodes/wave
    gatherO_k<<<(N_NODES + 7) / 8, 256, 0, stream>>>((const u32*)tb, rowinfo, edata, dinv, bc, out);
}